// Round 10
// baseline (91.248 us; speedup 1.0000x reference)
//
#include <hip/hip_runtime.h>
#include <cstddef>
#include <cstdint>

// B=256, S=16384, R=16, N=6.
//   V_k[b,(d,e)] = sum_s z[b,s]*core_k[d,s,e]  (k=1..5)
//   W[b] = V1..V5 chain; out[b,s] = sum_d c0[s,d]*W[b,d]
//
// R10: BOTH GEMM operands pre-converted to frag-native tiled bf16.
//  - z -> zh(RNE) + zl(residual) planes  [2-term split: acc z*RNE(b)]
//  - cores -> bbf bf16 RNE, SAME tiled layout [cblk][sblk][lane][8]
// GEMM per 32-s step: 8 A-dwordx4 + 4 B-dwordx4 (was 40 strided dwords ->
// vmcnt>63 overflow & per-step HBM latency, the R9 serializer). 2-set
// named double buffer, <=24 outstanding, zero cvt VALU in the K-loop.
namespace {
constexpr int kB = 256;
constexpr int kS = 16384;
constexpr int kNCol = 1040;       // 65 col-blocks of 16
constexpr int kSB = kS / 8;       // 2048 s-blocks of 8
}

using short8 = __attribute__((ext_vector_type(8))) short;   // 8 bf16
using f32x4  = __attribute__((ext_vector_type(4))) float;

__device__ __forceinline__ unsigned short bf16_rne(float x) {
    const uint32_t u = __float_as_uint(x);
    return (unsigned short)((u + 0x7FFFu + ((u >> 16) & 1u)) >> 16);
}

// ---------------------------------------------------------------------------
// Prepass 1: z -> zh = RNE(z), zl = trunc-bf16(z - zh); tiled
// idx = ((rowblk*kSB+sblk)*16+lr)*8  (16x16x32 A-fragment order).
// ---------------------------------------------------------------------------
__global__ __launch_bounds__(256) void fttv_split(
    const float* __restrict__ z,
    unsigned short* __restrict__ zh, unsigned short* __restrict__ zl)
{
    const int i = blockIdx.x * 256 + threadIdx.x;   // 524288 threads
    const int lr = i & 15;
    const int sblk = (i >> 4) & (kSB - 1);
    const int rowblk = i >> 15;
    const int row = rowblk * 16 + lr;
    const float* src = z + (size_t)row * kS + sblk * 8;
    float x[8];
    *reinterpret_cast<float4*>(&x[0]) = *reinterpret_cast<const float4*>(src);
    *reinterpret_cast<float4*>(&x[4]) = *reinterpret_cast<const float4*>(src + 4);
    short8 h, l;
    #pragma unroll
    for (int j = 0; j < 8; ++j) {
        const unsigned short hb = bf16_rne(x[j]);
        h[j] = (short)hb;
        const float r = x[j] - __uint_as_float((uint32_t)hb << 16);
        l[j] = (short)(__float_as_uint(r) >> 16);
    }
    const size_t idx = (((size_t)rowblk * kSB + sblk) * 16 + lr) * 8;
    *reinterpret_cast<short8*>(zh + idx) = h;
    *reinterpret_cast<short8*>(zl + idx) = l;
}

// ---------------------------------------------------------------------------
// Prepass 2: cores -> bbf bf16 RNE, tiled ((cblk*kSB+sblk)*16+lc)*8.
// col c = cblk*16+lc: c<1024 -> core[1+cblk/16][cblk&15][s][lc];
// cblk==64 -> core5[lc][s]. Wave reads 4x64B lines per j (lc spans e).
// ---------------------------------------------------------------------------
__global__ __launch_bounds__(256) void fttv_bconv(
    const float* __restrict__ c1, const float* __restrict__ c2,
    const float* __restrict__ c3, const float* __restrict__ c4,
    const float* __restrict__ c5, unsigned short* __restrict__ bbf)
{
    const int i = blockIdx.x * 256 + threadIdx.x;   // 65*2048*16 threads
    const int lc = i & 15;
    const int sblk = (i >> 4) & (kSB - 1);
    const int cblk = i >> 15;                       // 0..64
    float x[8];
    if (cblk < 64) {
        const float* cp = (cblk < 16 ? c1 : cblk < 32 ? c2 : cblk < 48 ? c3 : c4);
        const int d = cblk & 15;
        const float* src = cp + ((size_t)d * kS + sblk * 8) * 16 + lc;
        #pragma unroll
        for (int j = 0; j < 8; ++j) x[j] = src[(size_t)j * 16];
    } else {
        const float* src = c5 + (size_t)lc * kS + sblk * 8;
        *reinterpret_cast<float4*>(&x[0]) = *reinterpret_cast<const float4*>(src);
        *reinterpret_cast<float4*>(&x[4]) = *reinterpret_cast<const float4*>(src + 4);
    }
    short8 h;
    #pragma unroll
    for (int j = 0; j < 8; ++j) h[j] = (short)bf16_rne(x[j]);
    *reinterpret_cast<short8*>(
        bbf + (((size_t)cblk * kSB + sblk) * 16 + lc) * 8) = h;
}

// ---------------------------------------------------------------------------
__device__ __forceinline__ void load_a(
    const unsigned short* __restrict__ zhp, const unsigned short* __restrict__ zlp,
    int sblk0, short8 ah[4], short8 al[4])
{
    #pragma unroll
    for (int fm = 0; fm < 4; ++fm) {
        const size_t o = ((size_t)fm * kSB + sblk0) * 128;
        ah[fm] = *reinterpret_cast<const short8*>(zhp + o);
        al[fm] = *reinterpret_cast<const short8*>(zlp + o);
    }
}

template <int NFN>
__device__ __forceinline__ void load_bt(
    const unsigned short* __restrict__ bp, int sblk0, short8 bh[NFN])
{
    #pragma unroll
    for (int fn = 0; fn < NFN; ++fn)
        bh[fn] = *reinterpret_cast<const short8*>(
            bp + ((size_t)fn * kSB + sblk0) * 128);
}

template <int NFN>
__device__ __forceinline__ void step_mfma(
    const short8 ah[4], const short8 al[4], const short8 bh[NFN],
    f32x4 acc[4][4])
{
    __builtin_amdgcn_s_setprio(1);
    #pragma unroll
    for (int fn = 0; fn < NFN; ++fn)
        #pragma unroll
        for (int fm = 0; fm < 4; ++fm) {
            acc[fm][fn] = __builtin_amdgcn_mfma_f32_16x16x32_bf16(
                ah[fm], bh[fn], acc[fm][fn], 0, 0, 0);
            acc[fm][fn] = __builtin_amdgcn_mfma_f32_16x16x32_bf16(
                al[fm], bh[fn], acc[fm][fn], 0, 0, 0);
        }
    __builtin_amdgcn_s_setprio(0);
}

// ---------------------------------------------------------------------------
// GEMM: atomicAdd partials into v[b][col]. grid = 68*splitk 1-WAVE blocks:
// (sk, mt 0..3, cg 0..16); wave tile 64x64 (cg==16: 64x16, same path NFN=1).
// 16x16x32 bf16, 2-term (zh+zl)*bh. 12 dwordx4/step, 2-set double buffer.
// ---------------------------------------------------------------------------
__global__ __launch_bounds__(64, 2) void fttv_gemm_t(
    const unsigned short* __restrict__ zh, const unsigned short* __restrict__ zl,
    const unsigned short* __restrict__ bbf,
    float* __restrict__ v, int kc)
{
    // bijective XCD swizzle (m204); flat = sk*68 + mt*17 + cg
    const int nwg = gridDim.x;
    const int q = nwg >> 3, r = nwg & 7;
    const int xcd = blockIdx.x & 7, rest = blockIdx.x >> 3;
    const int vfl = (xcd < r ? xcd * (q + 1) : r * (q + 1) + (xcd - r) * q) + rest;
    const int sk = vfl / 68;
    const int rem = vfl - sk * 68;
    const int mt = rem / 17;
    const int cg = rem - mt * 17;

    const int l = threadIdx.x;
    const int lr = l & 15, lkq = l >> 4;
    const int nsteps = kc >> 5;                 // 16 for splitk=32 (even)
    const int sb0 = sk * (kc >> 3) + lkq;       // lane's absolute s-block base

    const unsigned short* zhp = zh + (size_t)(mt * 4) * kSB * 128 + lr * 8;
    const unsigned short* zlp = zl + (size_t)(mt * 4) * kSB * 128 + lr * 8;
    const unsigned short* bp  = bbf + (size_t)(cg * 4) * kSB * 128 + lr * 8;

    f32x4 acc[4][4];
    #pragma unroll
    for (int i = 0; i < 4; ++i)
        #pragma unroll
        for (int j = 0; j < 4; ++j) acc[i][j] = (f32x4){0.f, 0.f, 0.f, 0.f};

    short8 ah0[4], al0[4], ah1[4], al1[4];

    if (cg < 16) {
        short8 bh0[4], bh1[4];
        load_bt<4>(bp, sb0, bh0);
        load_a(zhp, zlp, sb0, ah0, al0);
        load_bt<4>(bp, sb0 + 4, bh1);
        load_a(zhp, zlp, sb0 + 4, ah1, al1);
        for (int t = 0; t < nsteps; t += 2) {
            step_mfma<4>(ah0, al0, bh0, acc);
            if (t + 2 < nsteps) {
                load_bt<4>(bp, sb0 + (t + 2) * 4, bh0);
                load_a(zhp, zlp, sb0 + (t + 2) * 4, ah0, al0);
            }
            step_mfma<4>(ah1, al1, bh1, acc);
            if (t + 3 < nsteps) {
                load_bt<4>(bp, sb0 + (t + 3) * 4, bh1);
                load_a(zhp, zlp, sb0 + (t + 3) * 4, ah1, al1);
            }
        }
        // epilogue: C frag col=l&15, row=(l>>4)*4+qq -> atomicAdd into v
        #pragma unroll
        for (int fm = 0; fm < 4; ++fm)
            #pragma unroll
            for (int fn = 0; fn < 4; ++fn) {
                const int col = cg * 64 + fn * 16 + lr;
                const int brow = mt * 64 + fm * 16 + lkq * 4;
                #pragma unroll
                for (int qq = 0; qq < 4; ++qq)
                    atomicAdd(&v[(size_t)(brow + qq) * kNCol + col],
                              acc[fm][fn][qq]);
            }
    } else {
        short8 bh0[1], bh1[1];
        load_bt<1>(bp, sb0, bh0);
        load_a(zhp, zlp, sb0, ah0, al0);
        load_bt<1>(bp, sb0 + 4, bh1);
        load_a(zhp, zlp, sb0 + 4, ah1, al1);
        for (int t = 0; t < nsteps; t += 2) {
            step_mfma<1>(ah0, al0, bh0, acc);
            if (t + 2 < nsteps) {
                load_bt<1>(bp, sb0 + (t + 2) * 4, bh0);
                load_a(zhp, zlp, sb0 + (t + 2) * 4, ah0, al0);
            }
            step_mfma<1>(ah1, al1, bh1, acc);
            if (t + 3 < nsteps) {
                load_bt<1>(bp, sb0 + (t + 3) * 4, bh1);
                load_a(zhp, zlp, sb0 + (t + 3) * 4, ah1, al1);
            }
        }
        #pragma unroll
        for (int fm = 0; fm < 4; ++fm) {
            const int col = 1024 + lr;
            const int brow = mt * 64 + fm * 16 + lkq * 4;
            #pragma unroll
            for (int qq = 0; qq < 4; ++qq)
                atomicAdd(&v[(size_t)(brow + qq) * kNCol + col], acc[fm][0][qq]);
        }
    }
}

// ---------------------------------------------------------------------------
// W[b] = V1@V2@V3@V4@V5col; one 64-thr block per batch; v layout [b][col]
__global__ void fttv_chain(const float* __restrict__ v, float* __restrict__ w)
{
    const int b = blockIdx.x;
    const float* vb = v + (size_t)b * kNCol;
    const int lane = threadIdx.x;
    const int d = lane & 15;
    float u = vb[1024 + d];
    #pragma unroll
    for (int k = 4; k >= 1; --k) {
        float nu = 0.f;
        #pragma unroll
        for (int e = 0; e < 16; ++e) {
            const float ue = __shfl(u, e, 16);
            nu += vb[(k - 1) * 256 + d * 16 + e] * ue;
        }
        u = nu;
    }
    if (lane < 16) w[b * 16 + d] = u;
}

// out[b,s] = sum_d c0[s,d] * W[b,d]
__global__ __launch_bounds__(256) void fttv_out(
    const float* __restrict__ c0, const float* __restrict__ w,
    float* __restrict__ out)
{
    __shared__ float wl[64][16];
    const int sc = blockIdx.x & 63;
    const int bq = blockIdx.x >> 6;
    const int tid = threadIdx.x;
    const int s = sc * 256 + tid;
    float f0[16];
    #pragma unroll
    for (int q = 0; q < 4; ++q)
        *reinterpret_cast<float4*>(&f0[q * 4]) =
            *reinterpret_cast<const float4*>(c0 + (size_t)s * 16 + q * 4);
    *reinterpret_cast<float4*>(&wl[0][0] + tid * 4) =
        *reinterpret_cast<const float4*>(w + bq * 1024 + tid * 4);
    __syncthreads();
    for (int bb = 0; bb < 64; ++bb) {
        float a = 0.f;
        #pragma unroll
        for (int d = 0; d < 16; ++d) a += f0[d] * wl[bb][d];
        out[(size_t)(bq * 64 + bb) * kS + s] = a;
    }
}

// ---------------------------------------------------------------------------
extern "C" void kernel_launch(void* const* d_in, const int* in_sizes, int n_in,
                              void* d_out, int out_size, void* d_ws, size_t ws_size,
                              hipStream_t stream)
{
    (void)in_sizes; (void)n_in; (void)out_size; (void)ws_size;
    const float* z  = (const float*)d_in[0];
    const float* c0 = (const float*)d_in[1];
    const float* c1 = (const float*)d_in[2];
    const float* c2 = (const float*)d_in[3];
    const float* c3 = (const float*)d_in[4];
    const float* c4 = (const float*)d_in[5];
    const float* c5 = (const float*)d_in[6];
    float* out = (float*)d_out;
    float* ws  = (float*)d_ws;

    // ws (f32 units): zh+zl (4.19M) | bbf (1040*16384 bf16 = 8.52M f32 eq)
    //               | v[256][1040] | w[256][16]
    const size_t zhlF = (size_t)kB * kS;          // zh+zl in f32 units
    const size_t bbfF = (size_t)kNCol * kS / 2;   // bbf in f32 units
    const int splitk = 32;
    const int kc = kS / splitk;                   // 512 -> nsteps=16

    unsigned short* zh = (unsigned short*)ws;
    unsigned short* zl = zh + (size_t)kB * kS;
    unsigned short* bbf = (unsigned short*)(ws + zhlF);
    float* v = ws + zhlF + bbfF;
    float* w = v + (size_t)kNCol * kB;

    hipMemsetAsync(v, 0, (size_t)kNCol * kB * sizeof(float), stream);
    fttv_split<<<dim3((kB * kS / 8) / 256), 256, 0, stream>>>(z, zh, zl);
    fttv_bconv<<<dim3(65 * kSB * 16 / 256), 256, 0, stream>>>(
        c1, c2, c3, c4, c5, bbf);
    fttv_gemm_t<<<dim3(68 * splitk), 64, 0, stream>>>(zh, zl, bbf, v, kc);
    fttv_chain<<<dim3(kB), 64, 0, stream>>>(v, w);
    fttv_out<<<dim3(256), 256, 0, stream>>>(c0, w, out);
}